// Round 1
// baseline (115.450 us; speedup 1.0000x reference)
//
#include <hip/hip_runtime.h>

// SimplePitchEstimator on MI355X.
// SR=16000, HOP=256, FRAME=160, lags 40..159, T=4096 per batch row, B=16.
// ac = irfft(rfft(x,512)^2) == linear self-convolution c[n] = sum_m x[m]*x[n-m]
// (support 2*160-2=318 < 512, no wraparound). Computed directly in fp32.
//
// Block = 256 threads = 64 frames x 4 lag-blocks (wave s owns lags 40+32s..71+32s).
// LDS holds 64 frames TRANSPOSED: X[row][frame] -> every ds_read/ds_write is
// lane-stride-1 (conflict-free). Pad rows (32 below, 8 above) store mu so that
// (pad - mu) == 0 exactly; mean subtraction folds into loads.
// Register tile: 32 lags x 4 m-steps -> 8 ds_read_b32 per 128 v_fma_f32.

#define SR_F     16000.0f
#define HOPSZ    256
#define FRAMESZ  160
#define FPB      64            // frames per block
#define PADB     32            // bottom pad rows (negative conv indices)
#define PADT     8             // top pad rows (dummy lags 160..167)
#define ROWS     (PADB + FRAMESZ + PADT)   // 200
#define TFRAMES  4096
#define SAMPLES  1048576

__global__ __launch_bounds__(256)
void pitch_kernel(const float* __restrict__ audio, float* __restrict__ out) {
    __shared__ float X[ROWS * FPB];   // 51200 B transposed frames
    __shared__ float A[4 * 64];       // partial sums -> reused for best values
    __shared__ float Bm[4 * 64];      // partial max|x-mu| (silent check)
    __shared__ int   Ci[4 * 64];      // best lags

    const int tid = threadIdx.x;
    const int s   = tid >> 6;         // wave id: staging chunk AND lag-block
    const int f   = tid & 63;         // frame within block
    const int blk = blockIdx.x;
    const int b   = blk >> 6;                 // batch row
    const int t0  = (blk & 63) << 6;          // first frame index of block

    // ---- stage: thread (f, s) loads samples [s*40, s*40+40) of frame f ----
    const float* g = audio + (size_t)b * SAMPLES + (size_t)(t0 + f) * HOPSZ + s * 40;
    float v[40];
    float ps = 0.f;
    #pragma unroll
    for (int j = 0; j < 10; ++j) {
        float4 q = reinterpret_cast<const float4*>(g)[j];   // 16B-aligned
        v[4*j+0] = q.x; v[4*j+1] = q.y; v[4*j+2] = q.z; v[4*j+3] = q.w;
        ps += q.x + q.y + q.z + q.w;
    }
    #pragma unroll
    for (int q = 0; q < 40; ++q)
        X[(PADB + s * 40 + q) * FPB + f] = v[q];            // lane-stride-1 writes
    A[s * 64 + f] = ps;
    __syncthreads();

    const float mu = (A[f] + A[64 + f] + A[128 + f] + A[192 + f]) * (1.0f / 160.0f);

    float pm = 0.f;
    #pragma unroll
    for (int q = 0; q < 40; ++q) pm = fmaxf(pm, fabsf(v[q] - mu));
    Bm[s * 64 + f] = pm;

    // pad rows = mu  (so X(pad) - mu == 0 exactly)
    #pragma unroll
    for (int q = 0; q < 10; ++q) {
        int rho = s * 10 + q;                 // 0..39
        int row = (rho < 32) ? rho : (rho + 160);  // rows 0..31 and 192..199
        X[row * FPB + f] = mu;
    }
    __syncthreads();

    // ---- main conv: wave s computes lags n0..n0+31 of frame f ----
    const int n0 = 40 + 32 * s;
    float acc[32];
    #pragma unroll
    for (int j = 0; j < 32; ++j) acc[j] = 0.f;

    // window regs: w[t] = X(n0 - mb - 3 + t) - mu, t = 0..34 (mb = current m base)
    float w[35];
    #pragma unroll
    for (int t = 0; t < 35; ++t)
        w[t] = X[(n0 - 3 + t + PADB) * FPB + f] - mu;

    const int R = 18 + 8 * s;   // rounds of 4 m-steps; m <= n_max = 71+32s

#define CONV_ROUND(mb_)                                              \
    {                                                                \
        const int xrow = ((mb_) + PADB) * FPB + f;                   \
        const float x0 = X[xrow          ] - mu;                     \
        const float x1 = X[xrow +     FPB] - mu;                     \
        const float x2 = X[xrow + 2 * FPB] - mu;                     \
        const float x3 = X[xrow + 3 * FPB] - mu;                     \
        _Pragma("unroll")                                            \
        for (int j = 0; j < 32; ++j) {                               \
            acc[j] = fmaf(x0, w[j + 3], acc[j]);                     \
            acc[j] = fmaf(x1, w[j + 2], acc[j]);                     \
            acc[j] = fmaf(x2, w[j + 1], acc[j]);                     \
            acc[j] = fmaf(x3, w[j + 0], acc[j]);                     \
        }                                                            \
    }

    for (int r = 0; r < R - 1; ++r) {
        const int mb = 4 * r;
        CONV_ROUND(mb);
        // shift window up 4, inject 4 new at bottom: X(n0 - mb - 7 + t)
        #pragma unroll
        for (int t = 34; t >= 4; --t) w[t] = w[t - 4];
        const int base = (n0 - mb - 7 + PADB) * FPB + f;
        w[0] = X[base          ] - mu;
        w[1] = X[base +     FPB] - mu;
        w[2] = X[base + 2 * FPB] - mu;
        w[3] = X[base + 3 * FPB] - mu;
    }
    CONV_ROUND(4 * (R - 1));   // last round: no shift (would read out of bounds)

    // ---- local argmax (first-max semantics, static indexing) ----
    float best = -3.4e38f;
    int   bl   = n0;
    #pragma unroll
    for (int j = 0; j < 32; ++j) {
        const bool valid = (j < 24) || (s < 3);   // exclude dummy lags 160..167
        if (valid && acc[j] > best) { best = acc[j]; bl = n0 + j; }
    }
    A[s * 64 + f]  = best;   // safe reuse: all mu-reads happened before barrier 2
    Ci[s * 64 + f] = bl;
    __syncthreads();

    // ---- finalize: wave 0, lane f handles frame f ----
    if (s == 0) {
        float bv = A[f];
        int   L  = Ci[f];
        #pragma unroll
        for (int c = 1; c < 4; ++c) {
            const float vv = A[c * 64 + f];
            if (vv > bv) { bv = vv; L = Ci[c * 64 + f]; }   // strict >: first max
        }
        const float mx = fmaxf(fmaxf(Bm[f], Bm[64 + f]),
                               fmaxf(Bm[128 + f], Bm[192 + f]));
        const float pitch = SR_F / (float)L;
        out[(size_t)b * TFRAMES + t0 + f] = (mx < 1e-8f) ? 0.0f : pitch;
    }
}

extern "C" void kernel_launch(void* const* d_in, const int* in_sizes, int n_in,
                              void* d_out, int out_size, void* d_ws, size_t ws_size,
                              hipStream_t stream) {
    const float* audio = (const float*)d_in[0];
    float* out = (float*)d_out;
    // 16 batch rows x 64 blocks, 64 frames/block, 256 threads/block
    pitch_kernel<<<dim3(1024), dim3(256), 0, stream>>>(audio, out);
}